// Round 2
// baseline (366.986 us; speedup 1.0000x reference)
//
#include <hip/hip_runtime.h>

#define N_NODES 100000
#define HID 64
#define N_EDGES 1600000
#define NB 391                 // ceil(N_NODES / 256) buckets of 256 nodes
#define C_EPB 6400             // edges per block in bucket_scatter (250 blocks)
#define GATHER_BLOCKS 6250     // N_NODES*16/256 gather blocks in fused prep kernel

typedef __attribute__((ext_vector_type(8))) short bf16x8;
typedef __attribute__((ext_vector_type(4))) float f32x4;

// ---- bf16 helpers (manual, RNE) ------------------------------------------
__device__ __forceinline__ unsigned short f2bf(float f) {
    unsigned u = __float_as_uint(f);
    u = (u + 0x7FFFu + ((u >> 16) & 1u)) >> 16;
    return (unsigned short)u;
}
__device__ __forceinline__ float bf2f(unsigned short h) {
    return __uint_as_float(((unsigned)h) << 16);
}
__device__ __forceinline__ float bflo(unsigned w) { return __uint_as_float(w << 16); }
__device__ __forceinline__ float bfhi(unsigned w) { return __uint_as_float(w & 0xFFFF0000u); }

// ------------------------------------------------- fused gather->bf16 + hist
__global__ void gather_hist_kernel(const float* __restrict__ emb,
                                   const int* __restrict__ nid,
                                   unsigned short* __restrict__ xh,
                                   const int* __restrict__ dst,
                                   int* __restrict__ bhist) {
    if (blockIdx.x < GATHER_BLOCKS) {
        int i = blockIdx.x * blockDim.x + threadIdx.x;
        const int total = N_NODES * (HID / 4);
        if (i >= total) return;
        int row = i >> 4;
        int c   = i & 15;
        int s   = nid[row];
        float4 v = reinterpret_cast<const float4*>(emb)[(size_t)s * 16 + c];
        uint2 p;
        p.x = (unsigned)f2bf(v.x) | ((unsigned)f2bf(v.y) << 16);
        p.y = (unsigned)f2bf(v.z) | ((unsigned)f2bf(v.w) << 16);
        reinterpret_cast<uint2*>(xh)[(size_t)row * 16 + c] = p;
        return;
    }
    // ---- histogram part (256 blocks)
    __shared__ int h[NB];
    for (int i = threadIdx.x; i < NB; i += blockDim.x) h[i] = 0;
    __syncthreads();
    int hb = blockIdx.x - GATHER_BLOCKS;
    const int nt = 256 * 256;
    const int4* d4 = (const int4*)dst;
    for (int q = hb * blockDim.x + threadIdx.x; q < N_EDGES / 4; q += nt) {
        int4 v = d4[q];
        atomicAdd(&h[v.x >> 8], 1);
        atomicAdd(&h[v.y >> 8], 1);
        atomicAdd(&h[v.z >> 8], 1);
        atomicAdd(&h[v.w >> 8], 1);
    }
    __syncthreads();
    for (int i = threadIdx.x; i < NB; i += blockDim.x)
        if (h[i]) atomicAdd(&bhist[i], h[i]);
}

// ---------------------------------------------------------------- CSR build, pass B
__global__ void bucket_scan(const int* __restrict__ bhist,
                            int* __restrict__ boff,
                            int* __restrict__ bcursor) {
    __shared__ int s[512];
    int v = (threadIdx.x < NB) ? bhist[threadIdx.x] : 0;
    s[threadIdx.x] = v;
    __syncthreads();
    for (int off = 1; off < 512; off <<= 1) {
        int t = (threadIdx.x >= off) ? s[threadIdx.x - off] : 0;
        __syncthreads();
        s[threadIdx.x] += t;
        __syncthreads();
    }
    if (threadIdx.x < NB) {
        int ex = s[threadIdx.x] - v;
        boff[threadIdx.x] = ex;
        bcursor[threadIdx.x] = ex;
    }
}

// ---------------------------------------------------------------- CSR build, pass C
// pairs.y packs (eid << 8) | (dst & 255).
__global__ void bucket_scatter(const int* __restrict__ src,
                               const int* __restrict__ dst,
                               int* __restrict__ bcursor,
                               int2* __restrict__ pairs) {
    __shared__ int h[NB];
    __shared__ int base[NB];
    for (int i = threadIdx.x; i < NB; i += blockDim.x) h[i] = 0;
    __syncthreads();
    int e0 = blockIdx.x * C_EPB;
    int e1 = e0 + C_EPB; if (e1 > N_EDGES) e1 = N_EDGES;
    for (int e = e0 + threadIdx.x; e < e1; e += blockDim.x)
        atomicAdd(&h[dst[e] >> 8], 1);
    __syncthreads();
    for (int i = threadIdx.x; i < NB; i += blockDim.x) {
        int c = h[i];
        base[i] = c ? atomicAdd(&bcursor[i], c) : 0;
    }
    __syncthreads();
    for (int i = threadIdx.x; i < NB; i += blockDim.x) h[i] = 0;
    __syncthreads();
    for (int e = e0 + threadIdx.x; e < e1; e += blockDim.x) {
        int d = dst[e];
        int b = d >> 8;
        int slot = base[b] + atomicAdd(&h[b], 1);
        pairs[slot] = make_int2(src[e], (d & 255) | (e << 8));
    }
}

// ---------------------------------------------------------------- CSR build, pass D
// eord[slot] = original edge id (same permutation as adj[]); consumed by the
// reorder kernel, NOT by the classifier hot loop. eord writes land within the
// bucket's contiguous slot range -> good write locality.
__global__ void bucket_csr(const int2* __restrict__ pairs,
                           const int* __restrict__ boff,
                           const int* __restrict__ bcursor,
                           int* __restrict__ row_start,
                           int* __restrict__ adj,
                           int* __restrict__ eord) {
    __shared__ int cnt[256];
    __shared__ int sc[256];
    int b = blockIdx.x;
    int node0 = b << 8;
    int p0 = boff[b];
    int p1 = bcursor[b];           // after pass C, bcursor[b] = end of bucket b
    int t = threadIdx.x;
    cnt[t] = 0;
    __syncthreads();
    for (int p = p0 + t; p < p1; p += 256)
        atomicAdd(&cnt[pairs[p].y & 255], 1);
    __syncthreads();
    int v = cnt[t];
    sc[t] = v;
    __syncthreads();
    for (int off = 1; off < 256; off <<= 1) {
        int u = (t >= off) ? sc[t - off] : 0;
        __syncthreads();
        sc[t] += u;
        __syncthreads();
    }
    sc[t] = p0 + sc[t] - v;        // exclusive scan + bucket base = row_start
    __syncthreads();
    int node = node0 + t;
    if (node <= N_NODES) row_start[node] = sc[t];
    __syncthreads();               // row_start read before atomics mutate sc
    for (int p = p0 + t; p < p1; p += 256) {
        int2 pr = pairs[p];
        int slot = atomicAdd(&sc[pr.y & 255], 1);
        adj[slot] = pr.x;
        eord[slot] = (int)(((unsigned)pr.y) >> 8);
    }
}

// ---------------------------------------------------------------- aggregation
// Pure gather+mean, NO LDS. 4 edge-slots x 16 lanes, uint2 loads.
// NT hints on adj (single-use streaming) so it doesn't evict gatherable
// feature rows from L2.
__global__ void agg_kernel(const int* __restrict__ row_start,
                           const int* __restrict__ adj,
                           const unsigned short* __restrict__ xh,
                           unsigned short* __restrict__ M) {
    int lane = threadIdx.x & 63;
    int slot = lane >> 4;               // 0..3  edge slot
    int c    = lane & 15;               // uint2 column (features 4c..4c+3)
    int wpb = blockDim.x >> 6;
    int wid = blockIdx.x * wpb + (threadIdx.x >> 6);
    int stride = gridDim.x * wpb;
    const uint2* xw = (const uint2*)xh;   // row stride = 16 uint2
    uint2* Mw = (uint2*)M;
    for (int row = wid; row < N_NODES; row += stride) {
        int beg = row_start[row], end = row_start[row + 1];
        float a0 = 0.f, a1 = 0.f, a2 = 0.f, a3 = 0.f;
        int j = beg + slot;
        for (; j + 12 < end; j += 16) {   // 4 uint2 gathers in flight per slot
            int s0 = __builtin_nontemporal_load(adj + j);
            int s1 = __builtin_nontemporal_load(adj + j + 4);
            int s2 = __builtin_nontemporal_load(adj + j + 8);
            int s3 = __builtin_nontemporal_load(adj + j + 12);
            uint2 v0 = xw[(size_t)s0 * 16 + c];
            uint2 v1 = xw[(size_t)s1 * 16 + c];
            uint2 v2 = xw[(size_t)s2 * 16 + c];
            uint2 v3 = xw[(size_t)s3 * 16 + c];
            a0 += bflo(v0.x) + bflo(v1.x) + bflo(v2.x) + bflo(v3.x);
            a1 += bfhi(v0.x) + bfhi(v1.x) + bfhi(v2.x) + bfhi(v3.x);
            a2 += bflo(v0.y) + bflo(v1.y) + bflo(v2.y) + bflo(v3.y);
            a3 += bfhi(v0.y) + bfhi(v1.y) + bfhi(v2.y) + bfhi(v3.y);
        }
        for (; j < end; j += 4) {
            uint2 v = xw[(size_t)__builtin_nontemporal_load(adj + j) * 16 + c];
            a0 += bflo(v.x); a1 += bfhi(v.x);
            a2 += bflo(v.y); a3 += bfhi(v.y);
        }
        a0 += __shfl_xor(a0, 16); a0 += __shfl_xor(a0, 32);
        a1 += __shfl_xor(a1, 16); a1 += __shfl_xor(a1, 32);
        a2 += __shfl_xor(a2, 16); a2 += __shfl_xor(a2, 32);
        a3 += __shfl_xor(a3, 16); a3 += __shfl_xor(a3, 32);
        if (slot == 0) {
            float inv = 1.0f / fmaxf((float)(end - beg), 1.0f);
            uint2 p;
            p.x = (unsigned)f2bf(a0 * inv) | ((unsigned)f2bf(a1 * inv) << 16);
            p.y = (unsigned)f2bf(a2 * inv) | ((unsigned)f2bf(a3 * inv) << 16);
            Mw[(size_t)row * 16 + c] = p;   // 16 lanes x 8B = 128B coalesced
        }
    }
}

// ---------------------------------------------------------------- MFMA GEMM
__global__ void gemm_kernel(const unsigned short* __restrict__ Am,
                            const unsigned short* __restrict__ As,
                            const float* __restrict__ Wl,
                            const float* __restrict__ Wr,
                            const float* __restrict__ bias,
                            unsigned short* __restrict__ H,
                            int relu) {
    int lane = threadIdx.x & 63;
    int m = lane & 15, quad = lane >> 4;

    bf16x8 wf[2][2][4];   // [matrix][kstep][ctile]
    for (int mat = 0; mat < 2; ++mat) {
        const float* W = mat ? Wr : Wl;
        for (int ks = 0; ks < 2; ++ks)
            for (int ct = 0; ct < 4; ++ct) {
                const float* p = W + (ct * 16 + m) * HID + ks * 32 + quad * 8;
                bf16x8 f;
                #pragma unroll
                for (int j = 0; j < 8; ++j) f[j] = (short)f2bf(p[j]);
                wf[mat][ks][ct] = f;
            }
    }
    float bv[4];
    #pragma unroll
    for (int ct = 0; ct < 4; ++ct) bv[ct] = bias[ct * 16 + m];

    int wpb = blockDim.x >> 6;
    int wid = blockIdx.x * wpb + (threadIdx.x >> 6);
    int stride = gridDim.x * wpb;
    const int NT = N_NODES / 16;
    for (int t = wid; t < NT; t += stride) {
        f32x4 acc[4] = {{0,0,0,0},{0,0,0,0},{0,0,0,0},{0,0,0,0}};
        size_t rowbase = ((size_t)t * 16 + m) * HID;
        #pragma unroll
        for (int ks = 0; ks < 2; ++ks) {
            bf16x8 a0 = *(const bf16x8*)(Am + rowbase + ks * 32 + quad * 8);
            bf16x8 a1 = *(const bf16x8*)(As + rowbase + ks * 32 + quad * 8);
            #pragma unroll
            for (int ct = 0; ct < 4; ++ct) {
                acc[ct] = __builtin_amdgcn_mfma_f32_16x16x32_bf16(a0, wf[0][ks][ct], acc[ct], 0, 0, 0);
                acc[ct] = __builtin_amdgcn_mfma_f32_16x16x32_bf16(a1, wf[1][ks][ct], acc[ct], 0, 0, 0);
            }
        }
        #pragma unroll
        for (int ct = 0; ct < 4; ++ct) {
            #pragma unroll
            for (int r = 0; r < 4; ++r) {
                float v = acc[ct][r] + bv[ct];
                if (relu) v = fmaxf(v, 0.f);
                H[((size_t)t * 16 + quad * 4 + r) * HID + ct * 16 + m] = f2bf(v);
            }
        }
    }
}

// ---------------------------------------------------------------- edge dot (CSR)
// Dst-grouped classifier: h[dst] read once per node (streaming); src side is
// the only random gather. Results are written to tmp[] in CSR SLOT ORDER
// (coalesced: 4 slot-leader lanes x 4 floats = 64B contiguous per iteration).
// NO scattered stores here -- the permutation to edge order happens in
// reorder_kernel, away from the gather flood.
__global__ void edge_dot_csr_kernel(const int* __restrict__ row_start,
                                    const int* __restrict__ adj,
                                    const unsigned short* __restrict__ h,
                                    float* __restrict__ tmp) {
    int lane = threadIdx.x & 63;
    int slot = lane >> 4;               // 0..3  edge slot
    int c    = lane & 15;               // uint2 column (features 4c..4c+3)
    int wpb = blockDim.x >> 6;
    int wid = blockIdx.x * wpb + (threadIdx.x >> 6);
    int stride = gridDim.x * wpb;
    const uint2* hw = (const uint2*)h;  // row stride = 16 uint2
    for (int row = wid; row < N_NODES; row += stride) {
        int beg = row_start[row], end = row_start[row + 1];
        if (beg == end) continue;
        uint2 vd = hw[(size_t)row * 16 + c];
        float d0 = bflo(vd.x), d1 = bfhi(vd.x), d2 = bflo(vd.y), d3 = bfhi(vd.y);
        int j = beg + slot;
        for (; j + 12 < end; j += 16) {   // 4 uint2 gathers in flight per slot
            int s0 = __builtin_nontemporal_load(adj + j);
            int s1 = __builtin_nontemporal_load(adj + j + 4);
            int s2 = __builtin_nontemporal_load(adj + j + 8);
            int s3 = __builtin_nontemporal_load(adj + j + 12);
            uint2 v0 = hw[(size_t)s0 * 16 + c];
            uint2 v1 = hw[(size_t)s1 * 16 + c];
            uint2 v2 = hw[(size_t)s2 * 16 + c];
            uint2 v3 = hw[(size_t)s3 * 16 + c];
            float p0 = bflo(v0.x) * d0 + bfhi(v0.x) * d1 + bflo(v0.y) * d2 + bfhi(v0.y) * d3;
            float p1 = bflo(v1.x) * d0 + bfhi(v1.x) * d1 + bflo(v1.y) * d2 + bfhi(v1.y) * d3;
            float p2 = bflo(v2.x) * d0 + bfhi(v2.x) * d1 + bflo(v2.y) * d2 + bfhi(v2.y) * d3;
            float p3 = bflo(v3.x) * d0 + bfhi(v3.x) * d1 + bflo(v3.y) * d2 + bfhi(v3.y) * d3;
            p0 += __shfl_xor(p0, 1); p0 += __shfl_xor(p0, 2); p0 += __shfl_xor(p0, 4); p0 += __shfl_xor(p0, 8);
            p1 += __shfl_xor(p1, 1); p1 += __shfl_xor(p1, 2); p1 += __shfl_xor(p1, 4); p1 += __shfl_xor(p1, 8);
            p2 += __shfl_xor(p2, 1); p2 += __shfl_xor(p2, 2); p2 += __shfl_xor(p2, 4); p2 += __shfl_xor(p2, 8);
            p3 += __shfl_xor(p3, 1); p3 += __shfl_xor(p3, 2); p3 += __shfl_xor(p3, 4); p3 += __shfl_xor(p3, 8);
            if (c == 0) {
                __builtin_nontemporal_store(p0, tmp + j);
                __builtin_nontemporal_store(p1, tmp + j + 4);
                __builtin_nontemporal_store(p2, tmp + j + 8);
                __builtin_nontemporal_store(p3, tmp + j + 12);
            }
        }
        for (; j < end; j += 4) {
            int s = __builtin_nontemporal_load(adj + j);
            uint2 v = hw[(size_t)s * 16 + c];
            float p = bflo(v.x) * d0 + bfhi(v.x) * d1 + bflo(v.y) * d2 + bfhi(v.y) * d3;
            p += __shfl_xor(p, 1); p += __shfl_xor(p, 2); p += __shfl_xor(p, 4); p += __shfl_xor(p, 8);
            if (c == 0) __builtin_nontemporal_store(p, tmp + j);
        }
    }
}

// ---------------------------------------------------------------- reorder
// out[eord[i]] = tmp[i]. Streaming coalesced reads (12.8 MB); scattered 4B
// writes into a 6.4 MB buffer with NO competing traffic -> lines fill in L2
// before eviction and combine.
__global__ void reorder_kernel(const float* __restrict__ tmp,
                               const int* __restrict__ eord,
                               float* __restrict__ out) {
    int i = blockIdx.x * blockDim.x + threadIdx.x;
    int base = i * 4;
    if (base >= N_EDGES) return;
    int4 e = *reinterpret_cast<const int4*>(eord + base);
    float4 v = *reinterpret_cast<const float4*>(tmp + base);
    out[e.x] = v.x;
    out[e.y] = v.y;
    out[e.z] = v.z;
    out[e.w] = v.w;
}

extern "C" void kernel_launch(void* const* d_in, const int* in_sizes, int n_in,
                              void* d_out, int out_size, void* d_ws, size_t ws_size,
                              hipStream_t stream) {
    const float* emb = (const float*)d_in[0];
    const float* Wl1 = (const float*)d_in[1];
    const float* Wr1 = (const float*)d_in[2];
    const float* b1  = (const float*)d_in[3];
    const float* Wl2 = (const float*)d_in[4];
    const float* Wr2 = (const float*)d_in[5];
    const float* b2  = (const float*)d_in[6];
    const int*   nid = (const int*)d_in[7];
    const int*   ei  = (const int*)d_in[8];
    const int* esrc = ei;
    const int* edst = ei + N_EDGES;
    float* out = (float*)d_out;

    const size_t NH = (size_t)N_NODES * HID;   // 6.4M elements
    unsigned short* xh  = (unsigned short*)d_ws;          // [N,64] bf16
    unsigned short* h1h = xh + NH;                        // [N,64] bf16
    unsigned short* h2h = h1h + NH;                       // [N,64] bf16
    unsigned short* M   = h2h + NH;                       // [N,64] bf16 (mean agg)
    int* ib        = (int*)(M + NH);                      // int region
    int* row_start = ib;                          // [N+1]
    int* adj       = ib + N_NODES + 64;           // [E]  src per CSR slot
    int* eord      = adj + N_EDGES;               // [E]  original edge id per slot
    int2* pairs    = (int2*)(eord + N_EDGES);     // [E]  (src, (eid<<8)|(dst&255))
    int* bhist     = (int*)(pairs + N_EDGES);     // [NB]
    int* boff      = bhist + NB + 1;              // [NB]
    int* bcursor   = boff + NB + 1;               // [NB]
    float* tmp     = (float*)pairs;               // [E]  reuse: pairs dead after CSR build

    hipMemsetAsync(bhist, 0, NB * sizeof(int), stream);

    // fused: xh = bf16(emb[node_id])  +  dst-bucket histogram
    gather_hist_kernel<<<GATHER_BLOCKS + 256, 256, 0, stream>>>(emb, nid, xh, edst, bhist);

    // ---- CSR build via bucket counting sort (shared by both layers)
    bucket_scan<<<1, 512, 0, stream>>>(bhist, boff, bcursor);
    bucket_scatter<<<(N_EDGES + C_EPB - 1) / C_EPB, 256, 0, stream>>>(esrc, edst, bcursor, pairs);
    bucket_csr<<<NB, 256, 0, stream>>>(pairs, boff, bcursor, row_start, adj, eord);

    // ---- layer 1: aggregate then MFMA GEMM (+relu)
    agg_kernel<<<2048, 256, 0, stream>>>(row_start, adj, xh, M);
    gemm_kernel<<<512, 256, 0, stream>>>(M, xh, Wl1, Wr1, b1, h1h, 1);

    // ---- layer 2
    agg_kernel<<<2048, 256, 0, stream>>>(row_start, adj, h1h, M);
    gemm_kernel<<<512, 256, 0, stream>>>(M, h1h, Wl2, Wr2, b2, h2h, 0);

    // ---- edge classifier: dst-grouped gather -> tmp (CSR order) -> permute
    edge_dot_csr_kernel<<<2048, 256, 0, stream>>>(row_start, adj, h2h, tmp);
    reorder_kernel<<<(N_EDGES / 4 + 255) / 256, 256, 0, stream>>>(tmp, eord, out);
}

// Round 3
// 283.850 us; speedup vs baseline: 1.2929x; 1.2929x over previous
//
#include <hip/hip_runtime.h>

#define N_NODES 100000
#define HID 64
#define N_EDGES 1600000
#define NB 391                 // ceil(N_NODES / 256) buckets of 256 nodes
#define C_EPB 6400             // edges per block in bucket_scatter (250 blocks)
#define GATHER_BLOCKS 6250     // N_NODES*16/256 gather blocks in fused prep kernel

typedef __attribute__((ext_vector_type(8))) short bf16x8;
typedef __attribute__((ext_vector_type(4))) float f32x4;

// ---- bf16 helpers (manual, RNE) ------------------------------------------
__device__ __forceinline__ unsigned short f2bf(float f) {
    unsigned u = __float_as_uint(f);
    u = (u + 0x7FFFu + ((u >> 16) & 1u)) >> 16;
    return (unsigned short)u;
}
__device__ __forceinline__ float bf2f(unsigned short h) {
    return __uint_as_float(((unsigned)h) << 16);
}
__device__ __forceinline__ float bflo(unsigned w) { return __uint_as_float(w << 16); }
__device__ __forceinline__ float bfhi(unsigned w) { return __uint_as_float(w & 0xFFFF0000u); }

// ------------------------------------------------- fused gather->bf16 + hist
__global__ void gather_hist_kernel(const float* __restrict__ emb,
                                   const int* __restrict__ nid,
                                   unsigned short* __restrict__ xh,
                                   const int* __restrict__ dst,
                                   int* __restrict__ bhist) {
    if (blockIdx.x < GATHER_BLOCKS) {
        int i = blockIdx.x * blockDim.x + threadIdx.x;
        const int total = N_NODES * (HID / 4);
        if (i >= total) return;
        int row = i >> 4;
        int c   = i & 15;
        int s   = nid[row];
        float4 v = reinterpret_cast<const float4*>(emb)[(size_t)s * 16 + c];
        uint2 p;
        p.x = (unsigned)f2bf(v.x) | ((unsigned)f2bf(v.y) << 16);
        p.y = (unsigned)f2bf(v.z) | ((unsigned)f2bf(v.w) << 16);
        reinterpret_cast<uint2*>(xh)[(size_t)row * 16 + c] = p;
        return;
    }
    // ---- histogram part (256 blocks)
    __shared__ int h[NB];
    for (int i = threadIdx.x; i < NB; i += blockDim.x) h[i] = 0;
    __syncthreads();
    int hb = blockIdx.x - GATHER_BLOCKS;
    const int nt = 256 * 256;
    const int4* d4 = (const int4*)dst;
    for (int q = hb * blockDim.x + threadIdx.x; q < N_EDGES / 4; q += nt) {
        int4 v = d4[q];
        atomicAdd(&h[v.x >> 8], 1);
        atomicAdd(&h[v.y >> 8], 1);
        atomicAdd(&h[v.z >> 8], 1);
        atomicAdd(&h[v.w >> 8], 1);
    }
    __syncthreads();
    for (int i = threadIdx.x; i < NB; i += blockDim.x)
        if (h[i]) atomicAdd(&bhist[i], h[i]);
}

// ---------------------------------------------------------------- CSR build, pass B
__global__ void bucket_scan(const int* __restrict__ bhist,
                            int* __restrict__ boff,
                            int* __restrict__ bcursor) {
    __shared__ int s[512];
    int v = (threadIdx.x < NB) ? bhist[threadIdx.x] : 0;
    s[threadIdx.x] = v;
    __syncthreads();
    for (int off = 1; off < 512; off <<= 1) {
        int t = (threadIdx.x >= off) ? s[threadIdx.x - off] : 0;
        __syncthreads();
        s[threadIdx.x] += t;
        __syncthreads();
    }
    if (threadIdx.x < NB) {
        int ex = s[threadIdx.x] - v;
        boff[threadIdx.x] = ex;
        bcursor[threadIdx.x] = ex;
    }
}

// ---------------------------------------------------------------- CSR build, pass C
__global__ void bucket_scatter(const int* __restrict__ src,
                               const int* __restrict__ dst,
                               int* __restrict__ bcursor,
                               int2* __restrict__ pairs) {
    __shared__ int h[NB];
    __shared__ int base[NB];
    for (int i = threadIdx.x; i < NB; i += blockDim.x) h[i] = 0;
    __syncthreads();
    int e0 = blockIdx.x * C_EPB;
    int e1 = e0 + C_EPB; if (e1 > N_EDGES) e1 = N_EDGES;
    for (int e = e0 + threadIdx.x; e < e1; e += blockDim.x)
        atomicAdd(&h[dst[e] >> 8], 1);
    __syncthreads();
    for (int i = threadIdx.x; i < NB; i += blockDim.x) {
        int c = h[i];
        base[i] = c ? atomicAdd(&bcursor[i], c) : 0;
    }
    __syncthreads();
    for (int i = threadIdx.x; i < NB; i += blockDim.x) h[i] = 0;
    __syncthreads();
    for (int e = e0 + threadIdx.x; e < e1; e += blockDim.x) {
        int d = dst[e];
        int b = d >> 8;
        int slot = base[b] + atomicAdd(&h[b], 1);
        pairs[slot] = make_int2(src[e], d);
    }
}

// ---------------------------------------------------------------- CSR build, pass D
__global__ void bucket_csr(const int2* __restrict__ pairs,
                           const int* __restrict__ boff,
                           const int* __restrict__ bcursor,
                           int* __restrict__ row_start,
                           int* __restrict__ adj) {
    __shared__ int cnt[256];
    __shared__ int sc[256];
    int b = blockIdx.x;
    int node0 = b << 8;
    int p0 = boff[b];
    int p1 = bcursor[b];           // after pass C, bcursor[b] = end of bucket b
    int t = threadIdx.x;
    cnt[t] = 0;
    __syncthreads();
    for (int p = p0 + t; p < p1; p += 256)
        atomicAdd(&cnt[pairs[p].y & 255], 1);
    __syncthreads();
    int v = cnt[t];
    sc[t] = v;
    __syncthreads();
    for (int off = 1; off < 256; off <<= 1) {
        int u = (t >= off) ? sc[t - off] : 0;
        __syncthreads();
        sc[t] += u;
        __syncthreads();
    }
    sc[t] = p0 + sc[t] - v;        // exclusive scan + bucket base = row_start
    __syncthreads();
    int node = node0 + t;
    if (node <= N_NODES) row_start[node] = sc[t];
    __syncthreads();               // row_start read before atomics mutate sc
    for (int p = p0 + t; p < p1; p += 256) {
        int2 pr = pairs[p];
        int slot = atomicAdd(&sc[pr.y & 255], 1);
        adj[slot] = pr.x;
    }
}

// ---------------------------------------------------------------- aggregation
// 4 rows per wave x 16 lanes per row (uint2 -> full 128B row per group).
// Each row-group walks ITS OWN list with an 8/4/1-deep unroll cascade:
// deg~16 rows keep 8 gathers in flight (vs the old slot design that needed
// deg>=13 just to reach 4-deep and ran remainders 1-deep). No shuffle
// reduction needed: lane c owns features 4c..4c+3 for its row; the 4
// consecutive rows of a wave write 512B contiguous.
__global__ void agg_kernel(const int* __restrict__ row_start,
                           const int* __restrict__ adj,
                           const unsigned short* __restrict__ xh,
                           unsigned short* __restrict__ M) {
    int lane = threadIdx.x & 63;
    int g = lane >> 4;                  // row group 0..3
    int c = lane & 15;                  // uint2 column (features 4c..4c+3)
    int wpb = blockDim.x >> 6;
    int wid = blockIdx.x * wpb + (threadIdx.x >> 6);
    int stride = gridDim.x * wpb;
    const uint2* xw = (const uint2*)xh;   // row stride = 16 uint2
    uint2* Mw = (uint2*)M;
    const int NQ = N_NODES / 4;           // 25000, exact
    for (int q = wid; q < NQ; q += stride) {
        int row = q * 4 + g;
        int beg = row_start[row], end = row_start[row + 1];
        float a0 = 0.f, a1 = 0.f, a2 = 0.f, a3 = 0.f;
        int j = beg;
        for (; j + 7 < end; j += 8) {     // 8 gathers in flight
            int s0 = adj[j],     s1 = adj[j + 1], s2 = adj[j + 2], s3 = adj[j + 3];
            int s4 = adj[j + 4], s5 = adj[j + 5], s6 = adj[j + 6], s7 = adj[j + 7];
            uint2 v0 = xw[(size_t)s0 * 16 + c];
            uint2 v1 = xw[(size_t)s1 * 16 + c];
            uint2 v2 = xw[(size_t)s2 * 16 + c];
            uint2 v3 = xw[(size_t)s3 * 16 + c];
            uint2 v4 = xw[(size_t)s4 * 16 + c];
            uint2 v5 = xw[(size_t)s5 * 16 + c];
            uint2 v6 = xw[(size_t)s6 * 16 + c];
            uint2 v7 = xw[(size_t)s7 * 16 + c];
            a0 += bflo(v0.x) + bflo(v1.x) + bflo(v2.x) + bflo(v3.x)
                + bflo(v4.x) + bflo(v5.x) + bflo(v6.x) + bflo(v7.x);
            a1 += bfhi(v0.x) + bfhi(v1.x) + bfhi(v2.x) + bfhi(v3.x)
                + bfhi(v4.x) + bfhi(v5.x) + bfhi(v6.x) + bfhi(v7.x);
            a2 += bflo(v0.y) + bflo(v1.y) + bflo(v2.y) + bflo(v3.y)
                + bflo(v4.y) + bflo(v5.y) + bflo(v6.y) + bflo(v7.y);
            a3 += bfhi(v0.y) + bfhi(v1.y) + bfhi(v2.y) + bfhi(v3.y)
                + bfhi(v4.y) + bfhi(v5.y) + bfhi(v6.y) + bfhi(v7.y);
        }
        if (j + 3 < end) {                // 4 gathers in flight
            int s0 = adj[j], s1 = adj[j + 1], s2 = adj[j + 2], s3 = adj[j + 3];
            uint2 v0 = xw[(size_t)s0 * 16 + c];
            uint2 v1 = xw[(size_t)s1 * 16 + c];
            uint2 v2 = xw[(size_t)s2 * 16 + c];
            uint2 v3 = xw[(size_t)s3 * 16 + c];
            a0 += bflo(v0.x) + bflo(v1.x) + bflo(v2.x) + bflo(v3.x);
            a1 += bfhi(v0.x) + bfhi(v1.x) + bfhi(v2.x) + bfhi(v3.x);
            a2 += bflo(v0.y) + bflo(v1.y) + bflo(v2.y) + bflo(v3.y);
            a3 += bfhi(v0.y) + bfhi(v1.y) + bfhi(v2.y) + bfhi(v3.y);
            j += 4;
        }
        for (; j < end; ++j) {
            uint2 v = xw[(size_t)adj[j] * 16 + c];
            a0 += bflo(v.x); a1 += bfhi(v.x);
            a2 += bflo(v.y); a3 += bfhi(v.y);
        }
        float inv = 1.0f / fmaxf((float)(end - beg), 1.0f);
        uint2 p;
        p.x = (unsigned)f2bf(a0 * inv) | ((unsigned)f2bf(a1 * inv) << 16);
        p.y = (unsigned)f2bf(a2 * inv) | ((unsigned)f2bf(a3 * inv) << 16);
        Mw[(size_t)row * 16 + c] = p;     // 4 rows/wave -> 512B contiguous
    }
}

// ---------------------------------------------------------------- MFMA GEMM
__global__ void gemm_kernel(const unsigned short* __restrict__ Am,
                            const unsigned short* __restrict__ As,
                            const float* __restrict__ Wl,
                            const float* __restrict__ Wr,
                            const float* __restrict__ bias,
                            unsigned short* __restrict__ H,
                            int relu) {
    int lane = threadIdx.x & 63;
    int m = lane & 15, quad = lane >> 4;

    bf16x8 wf[2][2][4];   // [matrix][kstep][ctile]
    for (int mat = 0; mat < 2; ++mat) {
        const float* W = mat ? Wr : Wl;
        for (int ks = 0; ks < 2; ++ks)
            for (int ct = 0; ct < 4; ++ct) {
                const float* p = W + (ct * 16 + m) * HID + ks * 32 + quad * 8;
                bf16x8 f;
                #pragma unroll
                for (int j = 0; j < 8; ++j) f[j] = (short)f2bf(p[j]);
                wf[mat][ks][ct] = f;
            }
    }
    float bv[4];
    #pragma unroll
    for (int ct = 0; ct < 4; ++ct) bv[ct] = bias[ct * 16 + m];

    int wpb = blockDim.x >> 6;
    int wid = blockIdx.x * wpb + (threadIdx.x >> 6);
    int stride = gridDim.x * wpb;
    const int NT = N_NODES / 16;
    for (int t = wid; t < NT; t += stride) {
        f32x4 acc[4] = {{0,0,0,0},{0,0,0,0},{0,0,0,0},{0,0,0,0}};
        size_t rowbase = ((size_t)t * 16 + m) * HID;
        #pragma unroll
        for (int ks = 0; ks < 2; ++ks) {
            bf16x8 a0 = *(const bf16x8*)(Am + rowbase + ks * 32 + quad * 8);
            bf16x8 a1 = *(const bf16x8*)(As + rowbase + ks * 32 + quad * 8);
            #pragma unroll
            for (int ct = 0; ct < 4; ++ct) {
                acc[ct] = __builtin_amdgcn_mfma_f32_16x16x32_bf16(a0, wf[0][ks][ct], acc[ct], 0, 0, 0);
                acc[ct] = __builtin_amdgcn_mfma_f32_16x16x32_bf16(a1, wf[1][ks][ct], acc[ct], 0, 0, 0);
            }
        }
        #pragma unroll
        for (int ct = 0; ct < 4; ++ct) {
            #pragma unroll
            for (int r = 0; r < 4; ++r) {
                float v = acc[ct][r] + bv[ct];
                if (relu) v = fmaxf(v, 0.f);
                H[((size_t)t * 16 + quad * 4 + r) * HID + ct * 16 + m] = f2bf(v);
            }
        }
    }
}

// ---------------------------------------------------------------- edge dot (bf16)
// Flat edge-order form (round-0, measured 42.7us at the 3.67 TB/s gather-path
// ceiling): 8 lanes per 2 consecutive edges, 4 uint4 gathers in flight/lane,
// coalesced float2 output write. No per-row loop -> MLP never collapses.
__global__ void edge_dot_kernel(const int* __restrict__ src,
                                const int* __restrict__ dst,
                                const unsigned short* __restrict__ h,
                                float* __restrict__ out) {
    int t = blockIdx.x * blockDim.x + threadIdx.x;
    int g = t >> 3;                 // edge-pair group
    int c = t & 7;
    int e0 = g * 2;
    if (e0 >= N_EDGES) return;
    int a0 = src[e0],     b0 = dst[e0];
    int a1 = src[e0 + 1], b1 = dst[e0 + 1];
    const uint4* h4 = reinterpret_cast<const uint4*>(h);
    uint4 va0 = h4[(size_t)a0 * 8 + c];
    uint4 vb0 = h4[(size_t)b0 * 8 + c];
    uint4 va1 = h4[(size_t)a1 * 8 + c];
    uint4 vb1 = h4[(size_t)b1 * 8 + c];
    float p0 = bflo(va0.x) * bflo(vb0.x) + bfhi(va0.x) * bfhi(vb0.x)
             + bflo(va0.y) * bflo(vb0.y) + bfhi(va0.y) * bfhi(vb0.y)
             + bflo(va0.z) * bflo(vb0.z) + bfhi(va0.z) * bfhi(vb0.z)
             + bflo(va0.w) * bflo(vb0.w) + bfhi(va0.w) * bfhi(vb0.w);
    float p1 = bflo(va1.x) * bflo(vb1.x) + bfhi(va1.x) * bfhi(vb1.x)
             + bflo(va1.y) * bflo(vb1.y) + bfhi(va1.y) * bfhi(vb1.y)
             + bflo(va1.z) * bflo(vb1.z) + bfhi(va1.z) * bfhi(vb1.z)
             + bflo(va1.w) * bflo(vb1.w) + bfhi(va1.w) * bfhi(vb1.w);
    p0 += __shfl_xor(p0, 1); p0 += __shfl_xor(p0, 2); p0 += __shfl_xor(p0, 4);
    p1 += __shfl_xor(p1, 1); p1 += __shfl_xor(p1, 2); p1 += __shfl_xor(p1, 4);
    if (c == 0) reinterpret_cast<float2*>(out)[g] = make_float2(p0, p1);
}

extern "C" void kernel_launch(void* const* d_in, const int* in_sizes, int n_in,
                              void* d_out, int out_size, void* d_ws, size_t ws_size,
                              hipStream_t stream) {
    const float* emb = (const float*)d_in[0];
    const float* Wl1 = (const float*)d_in[1];
    const float* Wr1 = (const float*)d_in[2];
    const float* b1  = (const float*)d_in[3];
    const float* Wl2 = (const float*)d_in[4];
    const float* Wr2 = (const float*)d_in[5];
    const float* b2  = (const float*)d_in[6];
    const int*   nid = (const int*)d_in[7];
    const int*   ei  = (const int*)d_in[8];
    const int* esrc = ei;
    const int* edst = ei + N_EDGES;
    float* out = (float*)d_out;

    const size_t NH = (size_t)N_NODES * HID;   // 6.4M elements
    unsigned short* xh  = (unsigned short*)d_ws;          // [N,64] bf16
    unsigned short* h1h = xh + NH;                        // [N,64] bf16
    unsigned short* h2h = h1h + NH;                       // [N,64] bf16
    unsigned short* M   = h2h + NH;                       // [N,64] bf16 (mean agg)
    int* ib        = (int*)(M + NH);                      // int region
    int* row_start = ib;                          // [N+1]
    int* adj       = ib + N_NODES + 64;           // [E]
    int2* pairs    = (int2*)(adj + N_EDGES + 64); // [E] (src,dst)
    int* bhist     = (int*)(pairs + N_EDGES);     // [NB]
    int* boff      = bhist + NB + 1;              // [NB]
    int* bcursor   = boff + NB + 1;               // [NB]

    hipMemsetAsync(bhist, 0, NB * sizeof(int), stream);

    // fused: xh = bf16(emb[node_id])  +  dst-bucket histogram
    gather_hist_kernel<<<GATHER_BLOCKS + 256, 256, 0, stream>>>(emb, nid, xh, edst, bhist);

    // ---- CSR build via bucket counting sort (shared by both layers)
    bucket_scan<<<1, 512, 0, stream>>>(bhist, boff, bcursor);
    bucket_scatter<<<(N_EDGES + C_EPB - 1) / C_EPB, 256, 0, stream>>>(esrc, edst, bcursor, pairs);
    bucket_csr<<<NB, 256, 0, stream>>>(pairs, boff, bcursor, row_start, adj);

    // ---- layer 1: aggregate then MFMA GEMM (+relu)
    agg_kernel<<<2048, 256, 0, stream>>>(row_start, adj, xh, M);
    gemm_kernel<<<512, 256, 0, stream>>>(M, xh, Wl1, Wr1, b1, h1h, 1);

    // ---- layer 2
    agg_kernel<<<2048, 256, 0, stream>>>(row_start, adj, h1h, M);
    gemm_kernel<<<512, 256, 0, stream>>>(M, h1h, Wl2, Wr2, b2, h2h, 0);

    // ---- edge classifier on bf16 features (flat edge-order, at path ceiling)
    edge_dot_kernel<<<((size_t)(N_EDGES / 2) * 8 + 255) / 256, 256, 0, stream>>>(esrc, edst, h2h, out);
}

// Round 4
// 279.130 us; speedup vs baseline: 1.3147x; 1.0169x over previous
//
#include <hip/hip_runtime.h>

#define N_NODES 100000
#define HID 64
#define N_EDGES 1600000
#define NB 391                 // ceil(N_NODES / 256) buckets of 256 nodes
#define NBP 392                // padded hist row (partial-hist stride)
#define NHB 256                // histogram blocks
#define C_EPB 6400             // edges per block in bucket_scatter (250 blocks)
#define GATHER_BLOCKS 6250     // N_NODES*16/256 gather blocks in fused prep kernel

typedef __attribute__((ext_vector_type(8))) short bf16x8;
typedef __attribute__((ext_vector_type(4))) float f32x4;

// ---- bf16 helpers (manual, RNE) ------------------------------------------
__device__ __forceinline__ unsigned short f2bf(float f) {
    unsigned u = __float_as_uint(f);
    u = (u + 0x7FFFu + ((u >> 16) & 1u)) >> 16;
    return (unsigned short)u;
}
__device__ __forceinline__ float bf2f(unsigned short h) {
    return __uint_as_float(((unsigned)h) << 16);
}
__device__ __forceinline__ float bflo(unsigned w) { return __uint_as_float(w << 16); }
__device__ __forceinline__ float bfhi(unsigned w) { return __uint_as_float(w & 0xFFFF0000u); }

// ------------------------------------------------- fused gather->bf16 + hist
// Blocks [0, GATHER_BLOCKS): xh = bf16(emb[node_id]).
// Blocks [GATHER_BLOCKS, +NHB): per-block PARTIAL dst-bucket histograms,
// written non-atomically to bhist_part[hb][*] (reduced in bucket_scan).
// Removes the bhist memset launch and all global atomics.
__global__ void gather_hist_kernel(const float* __restrict__ emb,
                                   const int* __restrict__ nid,
                                   unsigned short* __restrict__ xh,
                                   const int* __restrict__ dst,
                                   int* __restrict__ bhist_part) {
    if (blockIdx.x < GATHER_BLOCKS) {
        int i = blockIdx.x * blockDim.x + threadIdx.x;
        const int total = N_NODES * (HID / 4);
        if (i >= total) return;
        int row = i >> 4;
        int c   = i & 15;
        int s   = nid[row];
        float4 v = reinterpret_cast<const float4*>(emb)[(size_t)s * 16 + c];
        uint2 p;
        p.x = (unsigned)f2bf(v.x) | ((unsigned)f2bf(v.y) << 16);
        p.y = (unsigned)f2bf(v.z) | ((unsigned)f2bf(v.w) << 16);
        reinterpret_cast<uint2*>(xh)[(size_t)row * 16 + c] = p;
        return;
    }
    // ---- histogram part (NHB blocks)
    __shared__ int h[NB];
    for (int i = threadIdx.x; i < NB; i += blockDim.x) h[i] = 0;
    __syncthreads();
    int hb = blockIdx.x - GATHER_BLOCKS;
    const int nt = NHB * 256;
    const int4* d4 = (const int4*)dst;
    for (int q = hb * blockDim.x + threadIdx.x; q < N_EDGES / 4; q += nt) {
        int4 v = d4[q];
        atomicAdd(&h[v.x >> 8], 1);
        atomicAdd(&h[v.y >> 8], 1);
        atomicAdd(&h[v.z >> 8], 1);
        atomicAdd(&h[v.w >> 8], 1);
    }
    __syncthreads();
    for (int i = threadIdx.x; i < NB; i += blockDim.x)
        bhist_part[hb * NBP + i] = h[i];
}

// ---------------------------------------------------------------- CSR build, pass B
// Reduce the NHB partial histograms, then exclusive-scan.
__global__ void bucket_scan(const int* __restrict__ bhist_part,
                            int* __restrict__ boff,
                            int* __restrict__ bcursor) {
    __shared__ int s[512];
    int v = 0;
    if (threadIdx.x < NB) {
        #pragma unroll 8
        for (int p = 0; p < NHB; ++p) v += bhist_part[p * NBP + threadIdx.x];
    }
    s[threadIdx.x] = v;
    __syncthreads();
    for (int off = 1; off < 512; off <<= 1) {
        int t = (threadIdx.x >= off) ? s[threadIdx.x - off] : 0;
        __syncthreads();
        s[threadIdx.x] += t;
        __syncthreads();
    }
    if (threadIdx.x < NB) {
        int ex = s[threadIdx.x] - v;
        boff[threadIdx.x] = ex;
        bcursor[threadIdx.x] = ex;
    }
}

// ---------------------------------------------------------------- CSR build, pass C
__global__ void bucket_scatter(const int* __restrict__ src,
                               const int* __restrict__ dst,
                               int* __restrict__ bcursor,
                               int2* __restrict__ pairs) {
    __shared__ int h[NB];
    __shared__ int base[NB];
    for (int i = threadIdx.x; i < NB; i += blockDim.x) h[i] = 0;
    __syncthreads();
    int e0 = blockIdx.x * C_EPB;
    int e1 = e0 + C_EPB; if (e1 > N_EDGES) e1 = N_EDGES;
    for (int e = e0 + threadIdx.x; e < e1; e += blockDim.x)
        atomicAdd(&h[dst[e] >> 8], 1);
    __syncthreads();
    for (int i = threadIdx.x; i < NB; i += blockDim.x) {
        int c = h[i];
        base[i] = c ? atomicAdd(&bcursor[i], c) : 0;
    }
    __syncthreads();
    for (int i = threadIdx.x; i < NB; i += blockDim.x) h[i] = 0;
    __syncthreads();
    for (int e = e0 + threadIdx.x; e < e1; e += blockDim.x) {
        int d = dst[e];
        int b = d >> 8;
        int slot = base[b] + atomicAdd(&h[b], 1);
        pairs[slot] = make_int2(src[e], d);
    }
}

// ---------------------------------------------------------------- CSR build, pass D
__global__ void bucket_csr(const int2* __restrict__ pairs,
                           const int* __restrict__ boff,
                           const int* __restrict__ bcursor,
                           int* __restrict__ row_start,
                           int* __restrict__ adj) {
    __shared__ int cnt[256];
    __shared__ int sc[256];
    int b = blockIdx.x;
    int node0 = b << 8;
    int p0 = boff[b];
    int p1 = bcursor[b];           // after pass C, bcursor[b] = end of bucket b
    int t = threadIdx.x;
    cnt[t] = 0;
    __syncthreads();
    for (int p = p0 + t; p < p1; p += 256)
        atomicAdd(&cnt[pairs[p].y & 255], 1);
    __syncthreads();
    int v = cnt[t];
    sc[t] = v;
    __syncthreads();
    for (int off = 1; off < 256; off <<= 1) {
        int u = (t >= off) ? sc[t - off] : 0;
        __syncthreads();
        sc[t] += u;
        __syncthreads();
    }
    sc[t] = p0 + sc[t] - v;        // exclusive scan + bucket base = row_start
    __syncthreads();
    int node = node0 + t;
    if (node <= N_NODES) row_start[node] = sc[t];
    __syncthreads();               // row_start read before atomics mutate sc
    for (int p = p0 + t; p < p1; p += 256) {
        int2 pr = pairs[p];
        int slot = atomicAdd(&sc[pr.y & 255], 1);
        adj[slot] = pr.x;
    }
}

// ---------------------------------------------------------------- aggregation
// 8 rows per wave x 8 lanes per row, uint4 (16B) gathers: 8 loads in flight
// = 128B/lane (2x edge_dot's depth, half the load instructions per byte of
// the old uint2 form). deg~16 rows run exactly ~2 full 8-deep iterations.
// Lane c owns features 8c..8c+7; the 8 consecutive rows of a wave write
// 1KB contiguous. No shuffle reduction.
__global__ void agg_kernel(const int* __restrict__ row_start,
                           const int* __restrict__ adj,
                           const unsigned short* __restrict__ xh,
                           unsigned short* __restrict__ M) {
    int lane = threadIdx.x & 63;
    int g = lane >> 3;                  // row group 0..7
    int c = lane & 7;                   // uint4 column (features 8c..8c+7)
    int wpb = blockDim.x >> 6;
    int wid = blockIdx.x * wpb + (threadIdx.x >> 6);
    int stride = gridDim.x * wpb;
    const uint4* xw = (const uint4*)xh;   // row stride = 8 uint4
    uint4* Mw = (uint4*)M;
    const int NQ = N_NODES / 8;           // 12500, exact
    for (int q = wid; q < NQ; q += stride) {
        int row = q * 8 + g;
        int beg = row_start[row], end = row_start[row + 1];
        float a0 = 0.f, a1 = 0.f, a2 = 0.f, a3 = 0.f;
        float a4 = 0.f, a5 = 0.f, a6 = 0.f, a7 = 0.f;
        int j = beg;
        for (; j + 7 < end; j += 8) {     // 8 uint4 gathers in flight
            int s0 = adj[j],     s1 = adj[j + 1], s2 = adj[j + 2], s3 = adj[j + 3];
            int s4 = adj[j + 4], s5 = adj[j + 5], s6 = adj[j + 6], s7 = adj[j + 7];
            uint4 v0 = xw[(size_t)s0 * 8 + c];
            uint4 v1 = xw[(size_t)s1 * 8 + c];
            uint4 v2 = xw[(size_t)s2 * 8 + c];
            uint4 v3 = xw[(size_t)s3 * 8 + c];
            uint4 v4 = xw[(size_t)s4 * 8 + c];
            uint4 v5 = xw[(size_t)s5 * 8 + c];
            uint4 v6 = xw[(size_t)s6 * 8 + c];
            uint4 v7 = xw[(size_t)s7 * 8 + c];
            a0 += bflo(v0.x) + bflo(v1.x) + bflo(v2.x) + bflo(v3.x)
                + bflo(v4.x) + bflo(v5.x) + bflo(v6.x) + bflo(v7.x);
            a1 += bfhi(v0.x) + bfhi(v1.x) + bfhi(v2.x) + bfhi(v3.x)
                + bfhi(v4.x) + bfhi(v5.x) + bfhi(v6.x) + bfhi(v7.x);
            a2 += bflo(v0.y) + bflo(v1.y) + bflo(v2.y) + bflo(v3.y)
                + bflo(v4.y) + bflo(v5.y) + bflo(v6.y) + bflo(v7.y);
            a3 += bfhi(v0.y) + bfhi(v1.y) + bfhi(v2.y) + bfhi(v3.y)
                + bfhi(v4.y) + bfhi(v5.y) + bfhi(v6.y) + bfhi(v7.y);
            a4 += bflo(v0.z) + bflo(v1.z) + bflo(v2.z) + bflo(v3.z)
                + bflo(v4.z) + bflo(v5.z) + bflo(v6.z) + bflo(v7.z);
            a5 += bfhi(v0.z) + bfhi(v1.z) + bfhi(v2.z) + bfhi(v3.z)
                + bfhi(v4.z) + bfhi(v5.z) + bfhi(v6.z) + bfhi(v7.z);
            a6 += bflo(v0.w) + bflo(v1.w) + bflo(v2.w) + bflo(v3.w)
                + bflo(v4.w) + bflo(v5.w) + bflo(v6.w) + bflo(v7.w);
            a7 += bfhi(v0.w) + bfhi(v1.w) + bfhi(v2.w) + bfhi(v3.w)
                + bfhi(v4.w) + bfhi(v5.w) + bfhi(v6.w) + bfhi(v7.w);
        }
        if (j + 3 < end) {                // 4 in flight
            int s0 = adj[j], s1 = adj[j + 1], s2 = adj[j + 2], s3 = adj[j + 3];
            uint4 v0 = xw[(size_t)s0 * 8 + c];
            uint4 v1 = xw[(size_t)s1 * 8 + c];
            uint4 v2 = xw[(size_t)s2 * 8 + c];
            uint4 v3 = xw[(size_t)s3 * 8 + c];
            a0 += bflo(v0.x) + bflo(v1.x) + bflo(v2.x) + bflo(v3.x);
            a1 += bfhi(v0.x) + bfhi(v1.x) + bfhi(v2.x) + bfhi(v3.x);
            a2 += bflo(v0.y) + bflo(v1.y) + bflo(v2.y) + bflo(v3.y);
            a3 += bfhi(v0.y) + bfhi(v1.y) + bfhi(v2.y) + bfhi(v3.y);
            a4 += bflo(v0.z) + bflo(v1.z) + bflo(v2.z) + bflo(v3.z);
            a5 += bfhi(v0.z) + bfhi(v1.z) + bfhi(v2.z) + bfhi(v3.z);
            a6 += bflo(v0.w) + bflo(v1.w) + bflo(v2.w) + bflo(v3.w);
            a7 += bfhi(v0.w) + bfhi(v1.w) + bfhi(v2.w) + bfhi(v3.w);
            j += 4;
        }
        for (; j < end; ++j) {
            uint4 v = xw[(size_t)adj[j] * 8 + c];
            a0 += bflo(v.x); a1 += bfhi(v.x);
            a2 += bflo(v.y); a3 += bfhi(v.y);
            a4 += bflo(v.z); a5 += bfhi(v.z);
            a6 += bflo(v.w); a7 += bfhi(v.w);
        }
        float inv = 1.0f / fmaxf((float)(end - beg), 1.0f);
        uint4 p;
        p.x = (unsigned)f2bf(a0 * inv) | ((unsigned)f2bf(a1 * inv) << 16);
        p.y = (unsigned)f2bf(a2 * inv) | ((unsigned)f2bf(a3 * inv) << 16);
        p.z = (unsigned)f2bf(a4 * inv) | ((unsigned)f2bf(a5 * inv) << 16);
        p.w = (unsigned)f2bf(a6 * inv) | ((unsigned)f2bf(a7 * inv) << 16);
        Mw[(size_t)row * 8 + c] = p;      // 8 rows/wave -> 1KB contiguous
    }
}

// ---------------------------------------------------------------- MFMA GEMM
__global__ void gemm_kernel(const unsigned short* __restrict__ Am,
                            const unsigned short* __restrict__ As,
                            const float* __restrict__ Wl,
                            const float* __restrict__ Wr,
                            const float* __restrict__ bias,
                            unsigned short* __restrict__ H,
                            int relu) {
    int lane = threadIdx.x & 63;
    int m = lane & 15, quad = lane >> 4;

    bf16x8 wf[2][2][4];   // [matrix][kstep][ctile]
    for (int mat = 0; mat < 2; ++mat) {
        const float* W = mat ? Wr : Wl;
        for (int ks = 0; ks < 2; ++ks)
            for (int ct = 0; ct < 4; ++ct) {
                const float* p = W + (ct * 16 + m) * HID + ks * 32 + quad * 8;
                bf16x8 f;
                #pragma unroll
                for (int j = 0; j < 8; ++j) f[j] = (short)f2bf(p[j]);
                wf[mat][ks][ct] = f;
            }
    }
    float bv[4];
    #pragma unroll
    for (int ct = 0; ct < 4; ++ct) bv[ct] = bias[ct * 16 + m];

    int wpb = blockDim.x >> 6;
    int wid = blockIdx.x * wpb + (threadIdx.x >> 6);
    int stride = gridDim.x * wpb;
    const int NT = N_NODES / 16;
    for (int t = wid; t < NT; t += stride) {
        f32x4 acc[4] = {{0,0,0,0},{0,0,0,0},{0,0,0,0},{0,0,0,0}};
        size_t rowbase = ((size_t)t * 16 + m) * HID;
        #pragma unroll
        for (int ks = 0; ks < 2; ++ks) {
            bf16x8 a0 = *(const bf16x8*)(Am + rowbase + ks * 32 + quad * 8);
            bf16x8 a1 = *(const bf16x8*)(As + rowbase + ks * 32 + quad * 8);
            #pragma unroll
            for (int ct = 0; ct < 4; ++ct) {
                acc[ct] = __builtin_amdgcn_mfma_f32_16x16x32_bf16(a0, wf[0][ks][ct], acc[ct], 0, 0, 0);
                acc[ct] = __builtin_amdgcn_mfma_f32_16x16x32_bf16(a1, wf[1][ks][ct], acc[ct], 0, 0, 0);
            }
        }
        #pragma unroll
        for (int ct = 0; ct < 4; ++ct) {
            #pragma unroll
            for (int r = 0; r < 4; ++r) {
                float v = acc[ct][r] + bv[ct];
                if (relu) v = fmaxf(v, 0.f);
                H[((size_t)t * 16 + quad * 4 + r) * HID + ct * 16 + m] = f2bf(v);
            }
        }
    }
}

// ---------------------------------------------------------------- edge dot (bf16)
// Flat edge-order form (measured 43.1us at the 3.64 TB/s fetch-path ceiling):
// 8 lanes per 2 consecutive edges, 4 uint4 gathers in flight/lane,
// coalesced float2 output write. No per-row loop -> MLP never collapses.
__global__ void edge_dot_kernel(const int* __restrict__ src,
                                const int* __restrict__ dst,
                                const unsigned short* __restrict__ h,
                                float* __restrict__ out) {
    int t = blockIdx.x * blockDim.x + threadIdx.x;
    int g = t >> 3;                 // edge-pair group
    int c = t & 7;
    int e0 = g * 2;
    if (e0 >= N_EDGES) return;
    int a0 = src[e0],     b0 = dst[e0];
    int a1 = src[e0 + 1], b1 = dst[e0 + 1];
    const uint4* h4 = reinterpret_cast<const uint4*>(h);
    uint4 va0 = h4[(size_t)a0 * 8 + c];
    uint4 vb0 = h4[(size_t)b0 * 8 + c];
    uint4 va1 = h4[(size_t)a1 * 8 + c];
    uint4 vb1 = h4[(size_t)b1 * 8 + c];
    float p0 = bflo(va0.x) * bflo(vb0.x) + bfhi(va0.x) * bfhi(vb0.x)
             + bflo(va0.y) * bflo(vb0.y) + bfhi(va0.y) * bfhi(vb0.y)
             + bflo(va0.z) * bflo(vb0.z) + bfhi(va0.z) * bfhi(vb0.z)
             + bflo(va0.w) * bflo(vb0.w) + bfhi(va0.w) * bfhi(vb0.w);
    float p1 = bflo(va1.x) * bflo(vb1.x) + bfhi(va1.x) * bfhi(vb1.x)
             + bflo(va1.y) * bflo(vb1.y) + bfhi(va1.y) * bfhi(vb1.y)
             + bflo(va1.z) * bflo(vb1.z) + bfhi(va1.z) * bfhi(vb1.z)
             + bflo(va1.w) * bflo(vb1.w) + bfhi(va1.w) * bfhi(vb1.w);
    p0 += __shfl_xor(p0, 1); p0 += __shfl_xor(p0, 2); p0 += __shfl_xor(p0, 4);
    p1 += __shfl_xor(p1, 1); p1 += __shfl_xor(p1, 2); p1 += __shfl_xor(p1, 4);
    if (c == 0) reinterpret_cast<float2*>(out)[g] = make_float2(p0, p1);
}

extern "C" void kernel_launch(void* const* d_in, const int* in_sizes, int n_in,
                              void* d_out, int out_size, void* d_ws, size_t ws_size,
                              hipStream_t stream) {
    const float* emb = (const float*)d_in[0];
    const float* Wl1 = (const float*)d_in[1];
    const float* Wr1 = (const float*)d_in[2];
    const float* b1  = (const float*)d_in[3];
    const float* Wl2 = (const float*)d_in[4];
    const float* Wr2 = (const float*)d_in[5];
    const float* b2  = (const float*)d_in[6];
    const int*   nid = (const int*)d_in[7];
    const int*   ei  = (const int*)d_in[8];
    const int* esrc = ei;
    const int* edst = ei + N_EDGES;
    float* out = (float*)d_out;

    const size_t NH = (size_t)N_NODES * HID;   // 6.4M elements
    unsigned short* xh  = (unsigned short*)d_ws;          // [N,64] bf16
    unsigned short* h1h = xh + NH;                        // [N,64] bf16
    unsigned short* h2h = h1h + NH;                       // [N,64] bf16
    unsigned short* M   = h2h + NH;                       // [N,64] bf16 (mean agg)
    int* ib        = (int*)(M + NH);                      // int region
    int* row_start = ib;                          // [N+1]
    int* adj       = ib + N_NODES + 64;           // [E]
    int2* pairs    = (int2*)(adj + N_EDGES + 64); // [E] (src,dst)
    int* bhist_part = (int*)(pairs + N_EDGES);    // [NHB*NBP] partial hists
    int* boff      = bhist_part + NHB * NBP;      // [NB]
    int* bcursor   = boff + NB + 1;               // [NB]

    // fused: xh = bf16(emb[node_id])  +  partial dst-bucket histograms
    gather_hist_kernel<<<GATHER_BLOCKS + NHB, 256, 0, stream>>>(emb, nid, xh, edst, bhist_part);

    // ---- CSR build via bucket counting sort (shared by both layers)
    bucket_scan<<<1, 512, 0, stream>>>(bhist_part, boff, bcursor);
    bucket_scatter<<<(N_EDGES + C_EPB - 1) / C_EPB, 256, 0, stream>>>(esrc, edst, bcursor, pairs);
    bucket_csr<<<NB, 256, 0, stream>>>(pairs, boff, bcursor, row_start, adj);

    // ---- layer 1: aggregate then MFMA GEMM (+relu)
    agg_kernel<<<2048, 256, 0, stream>>>(row_start, adj, xh, M);
    gemm_kernel<<<512, 256, 0, stream>>>(M, xh, Wl1, Wr1, b1, h1h, 1);

    // ---- layer 2
    agg_kernel<<<2048, 256, 0, stream>>>(row_start, adj, h1h, M);
    gemm_kernel<<<512, 256, 0, stream>>>(M, h1h, Wl2, Wr2, b2, h2h, 0);

    // ---- edge classifier on bf16 features (flat edge-order, at path ceiling)
    edge_dot_kernel<<<((size_t)(N_EDGES / 2) * 8 + 255) / 256, 256, 0, stream>>>(esrc, edst, h2h, out);
}